// Round 1
// baseline (403.312 us; speedup 1.0000x reference)
//
#include <hip/hip_runtime.h>
#include <cstdint>
#include <cstddef>

#define DEV static __device__ __forceinline__

typedef __attribute__((ext_vector_type(8))) short short8;
typedef __attribute__((ext_vector_type(4))) float floatx4;

// ---- constants for this problem ----
#define BB 4
#define TT 2048
#define DIMM 1024
#define HH 16
#define DHH 64
#define MM (BB*TT)      // 8192

DEV unsigned short f2bu(float f) {
    // fp32 -> bf16, round-to-nearest-even
    unsigned int u = __float_as_uint(f);
    unsigned int r = (u + 0x7fffu + ((u >> 16) & 1u)) >> 16;
    return (unsigned short)r;
}

DEV unsigned long long pack4(float a, float b, float c, float d) {
    return (unsigned long long)f2bu(a) | ((unsigned long long)f2bu(b) << 16) |
           ((unsigned long long)f2bu(c) << 32) | ((unsigned long long)f2bu(d) << 48);
}

#define MFMA16(a, b, c) __builtin_amdgcn_mfma_f32_16x16x32_bf16((a), (b), (c), 0, 0, 0)

// ---------------------------------------------------------------------------
// K0: normalize context mask to u8[B*T]. Detect layout (bool/int8 vs int32 vs
// fp32) from byte pattern: int32 0/1 -> bytes %4!=0 all zero; float 0.0/1.0 ->
// bytes %4==1 zero but %4∈{2,3} nonzero (0x80,0x3f); else byte data.
// ---------------------------------------------------------------------------
__global__ __launch_bounds__(256) void normalize_ctx(const unsigned char* __restrict__ raw,
                                                     unsigned char* __restrict__ out) {
    __shared__ int nz1, nz23;
    if (threadIdx.x == 0) { nz1 = 0; nz23 = 0; }
    __syncthreads();
    int a1 = 0, a23 = 0;
    for (int i = threadIdx.x; i < BB * TT; i += 256) {
        unsigned char vb = raw[i];
        int m = i & 3;
        if (vb) { if (m == 1) a1 = 1; else if (m >= 2) a23 = 1; }
    }
    if (a1) atomicOr(&nz1, 1);
    if (a23) atomicOr(&nz23, 1);
    __syncthreads();
    const int mode = nz1 ? 2 : (nz23 ? 1 : 0); // 0=int32, 1=float32, 2=byte
    for (int i = threadIdx.x; i < BB * TT; i += 256) {
        unsigned char r;
        if (mode == 2)      r = raw[i] ? 1 : 0;
        else if (mode == 0) r = raw[(size_t)4 * i] ? 1 : 0;
        else                r = (raw[(size_t)4 * i + 2] | raw[(size_t)4 * i + 3]) ? 1 : 0;
        out[i] = r;
    }
}

// ---------------------------------------------------------------------------
// K1: weight convert+transpose: W fp32 [1024][1024] ([k][n]) -> bf16 [n][k].
// grid = (256 tiles of 64x64, 4 matrices)
// ---------------------------------------------------------------------------
__global__ __launch_bounds__(256) void wtrans(const float* __restrict__ W0, const float* __restrict__ W1,
                                              const float* __restrict__ W2, const float* __restrict__ W3,
                                              unsigned short* __restrict__ out) {
    const float* W = blockIdx.y == 0 ? W0 : blockIdx.y == 1 ? W1 : blockIdx.y == 2 ? W2 : W3;
    unsigned short* O = out + (size_t)blockIdx.y * DIMM * DIMM;
    const int tx = blockIdx.x & 15, ty = blockIdx.x >> 4; // nbase=tx*64, kbase=ty*64
    __shared__ float s[64][65];
    const int tid = threadIdx.x;
#pragma unroll
    for (int j = 0; j < 4; ++j) {
        int c = tid + 256 * j;
        int r = c >> 4, c4 = c & 15;
        float4 vv = *reinterpret_cast<const float4*>(&W[(size_t)(ty * 64 + r) * DIMM + tx * 64 + c4 * 4]);
        s[r][c4 * 4 + 0] = vv.x; s[r][c4 * 4 + 1] = vv.y;
        s[r][c4 * 4 + 2] = vv.z; s[r][c4 * 4 + 3] = vv.w;
    }
    __syncthreads();
#pragma unroll
    for (int j = 0; j < 4; ++j) {
        int c = tid + 256 * j;
        int n = c >> 4, k4 = c & 15;
        unsigned long long pk = pack4(s[k4 * 4 + 0][n], s[k4 * 4 + 1][n], s[k4 * 4 + 2][n], s[k4 * 4 + 3][n]);
        *reinterpret_cast<unsigned long long*>(&O[(size_t)(tx * 64 + n) * DIMM + ty * 64 + k4 * 4]) = pk;
    }
}

// ---------------------------------------------------------------------------
// K2/K4: GEMM  C[M][N] = A[M][K] @ Bt[N][K]^T + bias, optional scale.
// 128x128 tile, 4 waves of 64x64, K-step 32, 16x16x32 bf16 MFMA.
// AMODE: 0 = A fp32 (convert during staging), 1 = A bf16.
// OMODE: 0 = bf16 [M][N], 1 = bf16 per-head-transposed V layout [b,h,d,t],
//        2 = fp32 [M][N].
// ---------------------------------------------------------------------------
template <int AMODE, int OMODE>
__global__ __launch_bounds__(256) void gemm128(const void* __restrict__ Ap,
                                               const unsigned short* __restrict__ Bt,
                                               const float* __restrict__ bias,
                                               void* __restrict__ Cp,
                                               int M, int N, int K, float scale) {
    __shared__ unsigned short As[128 * 32];
    __shared__ unsigned short Bs[128 * 32];
    const int tid = threadIdx.x, lane = tid & 63, g = lane >> 4, lq = lane & 15;
    const int wid = tid >> 6;
    const int mbase = blockIdx.x * 128, nbase = blockIdx.y * 128;
    const int wm = (wid >> 1) * 64, wn = (wid & 1) * 64;
    const float* Af = (const float*)Ap;
    const unsigned short* Ab = (const unsigned short*)Ap;
    floatx4 acc[4][4];
#pragma unroll
    for (int i = 0; i < 4; ++i)
#pragma unroll
        for (int j = 0; j < 4; ++j) acc[i][j] = (floatx4){0.f, 0.f, 0.f, 0.f};

    for (int k0 = 0; k0 < K; k0 += 32) {
        if (AMODE == 0) {
#pragma unroll
            for (int j = 0; j < 4; ++j) {
                int c = tid + 256 * j;       // 1024 float4 chunks
                int row = c >> 3, kc = c & 7;
                float4 v = *reinterpret_cast<const float4*>(&Af[(size_t)(mbase + row) * K + k0 + kc * 4]);
                *reinterpret_cast<unsigned long long*>(&As[row * 32 + kc * 4]) =
                    pack4(v.x, v.y, v.z, v.w);
            }
        } else {
#pragma unroll
            for (int j = 0; j < 2; ++j) {
                int c = tid + 256 * j;       // 512 16B chunks
                int row = c >> 2, kc = c & 3;
                *reinterpret_cast<float4*>(&As[row * 32 + kc * 8]) =
                    *reinterpret_cast<const float4*>(&Ab[(size_t)(mbase + row) * K + k0 + kc * 8]);
            }
        }
#pragma unroll
        for (int j = 0; j < 2; ++j) {
            int c = tid + 256 * j;
            int row = c >> 2, kc = c & 3;
            *reinterpret_cast<float4*>(&Bs[row * 32 + kc * 8]) =
                *reinterpret_cast<const float4*>(&Bt[(size_t)(nbase + row) * K + k0 + kc * 8]);
        }
        __syncthreads();
        short8 af[4], bfr[4];
#pragma unroll
        for (int i = 0; i < 4; ++i) {
            af[i]  = *reinterpret_cast<const short8*>(&As[(wm + i * 16 + lq) * 32 + g * 8]);
            bfr[i] = *reinterpret_cast<const short8*>(&Bs[(wn + i * 16 + lq) * 32 + g * 8]);
        }
#pragma unroll
        for (int i = 0; i < 4; ++i)
#pragma unroll
            for (int j = 0; j < 4; ++j)
                acc[i][j] = MFMA16(af[i], bfr[j], acc[i][j]);
        __syncthreads();
    }

    // epilogue: D lane layout col = lane&15, row = (lane>>4)*4 + r
#pragma unroll
    for (int i = 0; i < 4; ++i) {
#pragma unroll
        for (int j = 0; j < 4; ++j) {
            const int col = nbase + wn + j * 16 + lq;
            const float bv = bias[col];
            const int row0 = mbase + wm + i * 16 + g * 4;
            if (OMODE == 2) {
                float* C = (float*)Cp;
#pragma unroll
                for (int r = 0; r < 4; ++r)
                    C[(size_t)(row0 + r) * N + col] = (acc[i][j][r] + bv) * scale;
            } else if (OMODE == 0) {
                unsigned short* C = (unsigned short*)Cp;
#pragma unroll
                for (int r = 0; r < 4; ++r)
                    C[(size_t)(row0 + r) * N + col] = f2bu((acc[i][j][r] + bv) * scale);
            } else {
                // V^T per head: out[((b*H+h)*DH + d)*T + t], 4 consecutive t
                unsigned short* C = (unsigned short*)Cp;
                const int b = row0 >> 11, t0 = row0 & (TT - 1);
                const int h = col >> 6, d = col & 63;
                unsigned long long pk = pack4((acc[i][j][0] + bv) * scale, (acc[i][j][1] + bv) * scale,
                                              (acc[i][j][2] + bv) * scale, (acc[i][j][3] + bv) * scale);
                *reinterpret_cast<unsigned long long*>(
                    &C[((size_t)(b * HH + h) * DHH + d) * TT + t0]) = pk;
            }
        }
    }
}

// ---------------------------------------------------------------------------
// K3: flash attention. One block = (b, h, 64 q rows). 4 waves x 16 q rows.
// S^T = K·Q^T (softmax row lane-local), online softmax, O^T = V^T·P^T.
// K/Q LDS tiles XOR-swizzled (128B rows); V^T uses pad-72 rows.
// ---------------------------------------------------------------------------
__global__ __launch_bounds__(256) void attn64(const unsigned short* __restrict__ Q,
                                              const unsigned short* __restrict__ Km,
                                              const unsigned short* __restrict__ Vt,
                                              const unsigned char* __restrict__ ctx,
                                              unsigned short* __restrict__ O) {
    const int blk = blockIdx.x;
    const int qt = blk & 31, h = (blk >> 5) & 15, b = blk >> 9;
    const int qbase = qt * 64;
    const int tid = threadIdx.x, lane = tid & 63, g = lane >> 4, lq = lane & 15, wid = tid >> 6;

    __shared__ unsigned short Qs[64 * 64];
    __shared__ unsigned short Ks[64 * 64];
    __shared__ unsigned short Vs[64 * 72];
    __shared__ unsigned short Ps[4][16 * 72];

    const size_t rowQ = (size_t)(b * TT + qbase);

    // stage Q tile, swizzled
#pragma unroll
    for (int j = 0; j < 2; ++j) {
        int c = tid + 256 * j;
        int row = c >> 3, dc = c & 7;
        int byteoff = (row * 128 + dc * 16) ^ ((row & 7) << 4);
        *reinterpret_cast<float4*>((char*)Qs + byteoff) =
            *reinterpret_cast<const float4*>(&Q[(rowQ + row) * DIMM + h * DHH + dc * 8]);
    }
    __syncthreads();
    short8 qf[2];
    {
        const int r = wid * 16 + lq;
        qf[0] = *reinterpret_cast<const short8*>((char*)Qs + ((r * 128 + g * 16) ^ ((r & 7) << 4)));
        qf[1] = *reinterpret_cast<const short8*>((char*)Qs + ((r * 128 + 64 + g * 16) ^ ((r & 7) << 4)));
    }

    floatx4 oacc[4];
#pragma unroll
    for (int f = 0; f < 4; ++f) oacc[f] = (floatx4){0.f, 0.f, 0.f, 0.f};
    float m_run = -1e30f, l_run = 0.f;

    const unsigned char* cb = ctx + b * TT;
    const unsigned short* Vbase = Vt + (size_t)(b * HH + h) * DHH * TT;
    const int qg = qbase + wid * 16 + lq;      // this lane's global q row
    const int qwave_max = qbase + wid * 16 + 15;
    const int nkv = qbase / 64 + 1;

    for (int kt = 0; kt < nkv; ++kt) {
        const int kvb = kt * 64;
        // stage K (swizzled) and V^T (pad 72)
#pragma unroll
        for (int j = 0; j < 2; ++j) {
            int c = tid + 256 * j;
            int row = c >> 3, dc = c & 7;
            int byteoff = (row * 128 + dc * 16) ^ ((row & 7) << 4);
            *reinterpret_cast<float4*>((char*)Ks + byteoff) =
                *reinterpret_cast<const float4*>(&Km[(size_t)(b * TT + kvb + row) * DIMM + h * DHH + dc * 8]);
            *reinterpret_cast<float4*>(&Vs[row * 72 + dc * 8]) =
                *reinterpret_cast<const float4*>(&Vbase[(size_t)row * TT + kvb + dc * 8]);
        }
        __syncthreads();

        if (kvb <= qwave_max) {   // wave-uniform causal skip
            // S^T frags: row kv = f*16 + g*4 + r, col q = lq
            float p[4][4];
            float mt = -INFINITY;
#pragma unroll
            for (int f = 0; f < 4; ++f) {
                const int r = f * 16 + lq;
                const int sw = (r & 7) << 4;
                short8 k0 = *reinterpret_cast<const short8*>((char*)Ks + ((r * 128 + g * 16) ^ sw));
                short8 k1 = *reinterpret_cast<const short8*>((char*)Ks + ((r * 128 + 64 + g * 16) ^ sw));
                floatx4 t = (floatx4){0.f, 0.f, 0.f, 0.f};
                t = MFMA16(k0, qf[0], t);
                t = MFMA16(k1, qf[1], t);
#pragma unroll
                for (int r2 = 0; r2 < 4; ++r2) {
                    const int kv = kvb + f * 16 + g * 4 + r2;
                    float sv = t[r2];
                    if (kv > qg || !cb[kv]) sv = -INFINITY;
                    p[f][r2] = sv;
                    mt = fmaxf(mt, sv);
                }
            }
            mt = fmaxf(mt, __shfl_xor(mt, 16, 64));
            mt = fmaxf(mt, __shfl_xor(mt, 32, 64));
            const float m_new = fmaxf(m_run, mt);
            const float alpha = __expf(m_run - m_new);
            float rs = 0.f;
#pragma unroll
            for (int f = 0; f < 4; ++f)
#pragma unroll
                for (int r2 = 0; r2 < 4; ++r2) {
                    float pe = __expf(p[f][r2] - m_new);
                    p[f][r2] = pe;
                    rs += pe;
                }
            rs += __shfl_xor(rs, 16, 64);
            rs += __shfl_xor(rs, 32, 64);
            l_run = l_run * alpha + rs;
            m_run = m_new;
#pragma unroll
            for (int f = 0; f < 4; ++f) oacc[f] *= alpha;
            // write P[q][kv] (per-wave buffer)
#pragma unroll
            for (int f = 0; f < 4; ++f)
                *reinterpret_cast<unsigned long long*>(&Ps[wid][lq * 72 + f * 16 + g * 4]) =
                    pack4(p[f][0], p[f][1], p[f][2], p[f][3]);
            // PV: O^T += V^T · P^T
#pragma unroll
            for (int f = 0; f < 4; ++f) {
#pragma unroll
                for (int kk = 0; kk < 2; ++kk) {
                    short8 av = *reinterpret_cast<const short8*>(&Vs[(f * 16 + lq) * 72 + kk * 32 + g * 8]);
                    short8 bv = *reinterpret_cast<const short8*>(&Ps[wid][lq * 72 + kk * 32 + g * 8]);
                    oacc[f] = MFMA16(av, bv, oacc[f]);
                }
            }
        }
        __syncthreads();
    }

    const float inv = 1.f / l_run;
#pragma unroll
    for (int f = 0; f < 4; ++f) {
        unsigned long long pk = pack4(oacc[f][0] * inv, oacc[f][1] * inv, oacc[f][2] * inv, oacc[f][3] * inv);
        *reinterpret_cast<unsigned long long*>(
            &O[(rowQ + wid * 16 + lq) * DIMM + h * DHH + f * 16 + g * 4]) = pk;
    }
}

// ---------------------------------------------------------------------------
extern "C" void kernel_launch(void* const* d_in, const int* in_sizes, int n_in,
                              void* d_out, int out_size, void* d_ws, size_t ws_size,
                              hipStream_t stream) {
    const float* q  = (const float*)d_in[0];
    const float* k  = (const float*)d_in[1];
    const float* v  = (const float*)d_in[2];
    const float* Wq = (const float*)d_in[3];
    const float* bq = (const float*)d_in[4];
    const float* Wk = (const float*)d_in[5];
    const float* bk = (const float*)d_in[6];
    const float* Wv = (const float*)d_in[7];
    const float* bv = (const float*)d_in[8];
    const float* Wo = (const float*)d_in[9];
    const float* bo = (const float*)d_in[10];
    const unsigned char* cmask = (const unsigned char*)d_in[12];

    unsigned short* Qp  = (unsigned short*)d_ws;                   // [8192][1024]
    unsigned short* Kp  = Qp + (size_t)MM * DIMM;                  // [8192][1024]
    unsigned short* Vtp = Kp + (size_t)MM * DIMM;                  // [b,h,d,t]
    unsigned short* AO  = Vtp + (size_t)MM * DIMM;                 // [8192][1024]
    unsigned short* Wt  = AO + (size_t)MM * DIMM;                  // 4x [n][k]
    unsigned char* ctxn = (unsigned char*)(Wt + (size_t)4 * DIMM * DIMM);

    normalize_ctx<<<dim3(1), dim3(256), 0, stream>>>(cmask, ctxn);
    wtrans<<<dim3(256, 4), dim3(256), 0, stream>>>(Wq, Wk, Wv, Wo, Wt);

    const float scale = 0.125f;  // DH^-0.5
    gemm128<0, 0><<<dim3(64, 8), dim3(256), 0, stream>>>(q, Wt,                       bq, Qp,  MM, DIMM, DIMM, scale);
    gemm128<0, 0><<<dim3(64, 8), dim3(256), 0, stream>>>(k, Wt + (size_t)DIMM * DIMM, bk, Kp,  MM, DIMM, DIMM, 1.f);
    gemm128<0, 1><<<dim3(64, 8), dim3(256), 0, stream>>>(v, Wt + (size_t)2 * DIMM * DIMM, bv, Vtp, MM, DIMM, DIMM, 1.f);

    attn64<<<dim3(BB * HH * (TT / 64)), dim3(256), 0, stream>>>(Qp, Kp, Vtp, ctxn, AO);

    gemm128<1, 2><<<dim3(64, 8), dim3(256), 0, stream>>>(AO, Wt + (size_t)3 * DIMM * DIMM, bo, d_out, MM, DIMM, DIMM, 1.f);
}

// Round 2
// 263.576 us; speedup vs baseline: 1.5302x; 1.5302x over previous
//
#include <hip/hip_runtime.h>
#include <hip/hip_bf16.h>
#include <cstdint>
#include <cstddef>

#define DEV static __device__ __forceinline__

typedef __attribute__((ext_vector_type(8))) short short8;
typedef __attribute__((ext_vector_type(4))) float floatx4;

// ---- constants for this problem ----
#define BB 4
#define TT 2048
#define DIMM 1024
#define HH 16
#define DHH 64
#define MM (BB*TT)      // 8192
#define QBLK 128
#define NQT (TT/QBLK)   // 16

DEV unsigned short f2bu(float f) {
    // fp32 -> bf16, round-to-nearest-even
    unsigned int u = __float_as_uint(f);
    unsigned int r = (u + 0x7fffu + ((u >> 16) & 1u)) >> 16;
    return (unsigned short)r;
}

DEV unsigned long long pack4(float a, float b, float c, float d) {
    return (unsigned long long)f2bu(a) | ((unsigned long long)f2bu(b) << 16) |
           ((unsigned long long)f2bu(c) << 32) | ((unsigned long long)f2bu(d) << 48);
}

DEV unsigned int pk2(float lo, float hi) {
    __hip_bfloat162 h = __float22bfloat162_rn(make_float2(lo, hi));
    unsigned int r;
    __builtin_memcpy(&r, &h, 4);
    return r;
}

#define MFMA16(a, b, c) __builtin_amdgcn_mfma_f32_16x16x32_bf16((a), (b), (c), 0, 0, 0)

// ---------------------------------------------------------------------------
// K0: normalize context mask to u8[B*T]. Detect layout (bool/int8 vs int32 vs
// fp32) from byte pattern.
// ---------------------------------------------------------------------------
__global__ __launch_bounds__(256) void normalize_ctx(const unsigned char* __restrict__ raw,
                                                     unsigned char* __restrict__ out) {
    __shared__ int nz1, nz23;
    if (threadIdx.x == 0) { nz1 = 0; nz23 = 0; }
    __syncthreads();
    int a1 = 0, a23 = 0;
    for (int i = threadIdx.x; i < BB * TT; i += 256) {
        unsigned char vb = raw[i];
        int m = i & 3;
        if (vb) { if (m == 1) a1 = 1; else if (m >= 2) a23 = 1; }
    }
    if (a1) atomicOr(&nz1, 1);
    if (a23) atomicOr(&nz23, 1);
    __syncthreads();
    const int mode = nz1 ? 2 : (nz23 ? 1 : 0); // 0=int32, 1=float32, 2=byte
    for (int i = threadIdx.x; i < BB * TT; i += 256) {
        unsigned char r;
        if (mode == 2)      r = raw[i] ? 1 : 0;
        else if (mode == 0) r = raw[(size_t)4 * i] ? 1 : 0;
        else                r = (raw[(size_t)4 * i + 2] | raw[(size_t)4 * i + 3]) ? 1 : 0;
        out[i] = r;
    }
}

// ---------------------------------------------------------------------------
// K1: weight convert+transpose: W fp32 [1024][1024] ([k][n]) -> bf16 [n][k].
// ---------------------------------------------------------------------------
__global__ __launch_bounds__(256) void wtrans(const float* __restrict__ W0, const float* __restrict__ W1,
                                              const float* __restrict__ W2, const float* __restrict__ W3,
                                              unsigned short* __restrict__ out) {
    const float* W = blockIdx.y == 0 ? W0 : blockIdx.y == 1 ? W1 : blockIdx.y == 2 ? W2 : W3;
    unsigned short* O = out + (size_t)blockIdx.y * DIMM * DIMM;
    const int tx = blockIdx.x & 15, ty = blockIdx.x >> 4;
    __shared__ float s[64][65];
    const int tid = threadIdx.x;
#pragma unroll
    for (int j = 0; j < 4; ++j) {
        int c = tid + 256 * j;
        int r = c >> 4, c4 = c & 15;
        float4 vv = *reinterpret_cast<const float4*>(&W[(size_t)(ty * 64 + r) * DIMM + tx * 64 + c4 * 4]);
        s[r][c4 * 4 + 0] = vv.x; s[r][c4 * 4 + 1] = vv.y;
        s[r][c4 * 4 + 2] = vv.z; s[r][c4 * 4 + 3] = vv.w;
    }
    __syncthreads();
#pragma unroll
    for (int j = 0; j < 4; ++j) {
        int c = tid + 256 * j;
        int n = c >> 4, k4 = c & 15;
        unsigned long long pk = pack4(s[k4 * 4 + 0][n], s[k4 * 4 + 1][n], s[k4 * 4 + 2][n], s[k4 * 4 + 3][n]);
        *reinterpret_cast<unsigned long long*>(&O[(size_t)(tx * 64 + n) * DIMM + ty * 64 + k4 * 4]) = pk;
    }
}

// ---------------------------------------------------------------------------
// K2/K4: GEMM  C[M][N] = A[M][K] @ Bt[N][K]^T + bias, scaled.
// ---------------------------------------------------------------------------
template <int AMODE, int OMODE>
__global__ __launch_bounds__(256) void gemm128(const void* __restrict__ Ap,
                                               const unsigned short* __restrict__ Bt,
                                               const float* __restrict__ bias,
                                               void* __restrict__ Cp,
                                               int M, int N, int K, float scale) {
    __shared__ unsigned short As[128 * 32];
    __shared__ unsigned short Bs[128 * 32];
    const int tid = threadIdx.x, lane = tid & 63, g = lane >> 4, lq = lane & 15;
    const int wid = tid >> 6;
    const int mbase = blockIdx.x * 128, nbase = blockIdx.y * 128;
    const int wm = (wid >> 1) * 64, wn = (wid & 1) * 64;
    const float* Af = (const float*)Ap;
    const unsigned short* Ab = (const unsigned short*)Ap;
    floatx4 acc[4][4];
#pragma unroll
    for (int i = 0; i < 4; ++i)
#pragma unroll
        for (int j = 0; j < 4; ++j) acc[i][j] = (floatx4){0.f, 0.f, 0.f, 0.f};

    for (int k0 = 0; k0 < K; k0 += 32) {
        if (AMODE == 0) {
#pragma unroll
            for (int j = 0; j < 4; ++j) {
                int c = tid + 256 * j;
                int row = c >> 3, kc = c & 7;
                float4 v = *reinterpret_cast<const float4*>(&Af[(size_t)(mbase + row) * K + k0 + kc * 4]);
                *reinterpret_cast<unsigned long long*>(&As[row * 32 + kc * 4]) =
                    pack4(v.x, v.y, v.z, v.w);
            }
        } else {
#pragma unroll
            for (int j = 0; j < 2; ++j) {
                int c = tid + 256 * j;
                int row = c >> 2, kc = c & 3;
                *reinterpret_cast<float4*>(&As[row * 32 + kc * 8]) =
                    *reinterpret_cast<const float4*>(&Ab[(size_t)(mbase + row) * K + k0 + kc * 8]);
            }
        }
#pragma unroll
        for (int j = 0; j < 2; ++j) {
            int c = tid + 256 * j;
            int row = c >> 2, kc = c & 3;
            *reinterpret_cast<float4*>(&Bs[row * 32 + kc * 8]) =
                *reinterpret_cast<const float4*>(&Bt[(size_t)(nbase + row) * K + k0 + kc * 8]);
        }
        __syncthreads();
        short8 af[4], bfr[4];
#pragma unroll
        for (int i = 0; i < 4; ++i) {
            af[i]  = *reinterpret_cast<const short8*>(&As[(wm + i * 16 + lq) * 32 + g * 8]);
            bfr[i] = *reinterpret_cast<const short8*>(&Bs[(wn + i * 16 + lq) * 32 + g * 8]);
        }
#pragma unroll
        for (int i = 0; i < 4; ++i)
#pragma unroll
            for (int j = 0; j < 4; ++j)
                acc[i][j] = MFMA16(af[i], bfr[j], acc[i][j]);
        __syncthreads();
    }

#pragma unroll
    for (int i = 0; i < 4; ++i) {
#pragma unroll
        for (int j = 0; j < 4; ++j) {
            const int col = nbase + wn + j * 16 + lq;
            const float bv = bias[col];
            const int row0 = mbase + wm + i * 16 + g * 4;
            if (OMODE == 2) {
                float* C = (float*)Cp;
#pragma unroll
                for (int r = 0; r < 4; ++r)
                    C[(size_t)(row0 + r) * N + col] = (acc[i][j][r] + bv) * scale;
            } else if (OMODE == 0) {
                unsigned short* C = (unsigned short*)Cp;
#pragma unroll
                for (int r = 0; r < 4; ++r)
                    C[(size_t)(row0 + r) * N + col] = f2bu((acc[i][j][r] + bv) * scale);
            } else {
                unsigned short* C = (unsigned short*)Cp;
                const int b = row0 >> 11, t0 = row0 & (TT - 1);
                const int h = col >> 6, d = col & 63;
                unsigned long long pk = pack4((acc[i][j][0] + bv) * scale, (acc[i][j][1] + bv) * scale,
                                              (acc[i][j][2] + bv) * scale, (acc[i][j][3] + bv) * scale);
                *reinterpret_cast<unsigned long long*>(
                    &C[((size_t)(b * HH + h) * DHH + d) * TT + t0]) = pk;
            }
        }
    }
}

// ---------------------------------------------------------------------------
// K3 v2: flash attention. 512 threads, 8 waves x 16 q rows = 128 q rows/block.
// Work-paired q-tiles (qt = pair and 15-pair -> uniform 34 KV iters/block).
// Double-buffered K/V (issue-early/write-late), context-mask bias in LDS,
// exp2-domain softmax (log2e folded into Q projection scale).
// All K/Q/V LDS tiles XOR-swizzled (byte ^= (row&7)<<4).
// ---------------------------------------------------------------------------
__global__ __launch_bounds__(512, 4) void attn128(const unsigned short* __restrict__ Q,
                                                  const unsigned short* __restrict__ Km,
                                                  const unsigned short* __restrict__ Vt,
                                                  const unsigned char* __restrict__ ctx,
                                                  unsigned short* __restrict__ O) {
    const int pair = blockIdx.x & 7, h = (blockIdx.x >> 3) & 15, b = blockIdx.x >> 7;
    const int tid = threadIdx.x, lane = tid & 63, g = lane >> 4, lq = lane & 15, wid = tid >> 6;

    __shared__ unsigned short Qs[QBLK * 64];       // 16KB swizzled
    __shared__ unsigned short Ks[2][64 * 64];      // 2x8KB swizzled
    __shared__ unsigned short Vs[2][64 * 64];      // 2x8KB swizzled
    __shared__ unsigned short Ps[8][16 * 72];      // 18KB (pad-72)
    __shared__ float maskF[TT];                    // 8KB

    const unsigned char* cb = ctx + b * TT;
    for (int i = tid; i < TT; i += 512) maskF[i] = cb[i] ? 0.f : -3.0e38f;

    const unsigned short* Vbase = Vt + (size_t)(b * HH + h) * DHH * TT;
    const int srow = tid >> 3, sdc = tid & 7;
    const int soff = (srow * 128 + sdc * 16) ^ ((srow & 7) << 4);

    for (int part = 0; part < 2; ++part) {
        const int qt = (part == 0) ? pair : (NQT - 1 - pair);
        const int qbase = qt * QBLK;
        const size_t rowQ = (size_t)(b * TT + qbase);
        const int nkv = 2 * qt + 2;

        __syncthreads();   // protect LDS reuse across parts (also covers maskF)
        // stage Q (2 chunks/thread) + K/V tile 0 (1 chunk each/thread)
#pragma unroll
        for (int j = 0; j < 2; ++j) {
            int ci = j * 512 + tid;
            int row = ci >> 3, dc = ci & 7;
            *reinterpret_cast<float4*>((char*)Qs + ((row * 128 + dc * 16) ^ ((row & 7) << 4))) =
                *reinterpret_cast<const float4*>(&Q[(rowQ + row) * DIMM + h * DHH + dc * 8]);
        }
        {
            float4 k0v = *reinterpret_cast<const float4*>(&Km[(size_t)(b * TT + srow) * DIMM + h * DHH + sdc * 8]);
            float4 v0v = *reinterpret_cast<const float4*>(&Vbase[(size_t)srow * TT + sdc * 8]);
            *reinterpret_cast<float4*>((char*)Ks[0] + soff) = k0v;
            *reinterpret_cast<float4*>((char*)Vs[0] + soff) = v0v;
        }
        __syncthreads();

        short8 qf0, qf1;
        {
            const int r = wid * 16 + lq;
            const int sw = (r & 7) << 4;
            qf0 = *reinterpret_cast<const short8*>((char*)Qs + ((r * 128 + g * 16) ^ sw));
            qf1 = *reinterpret_cast<const short8*>((char*)Qs + ((r * 128 + 64 + g * 16) ^ sw));
        }

        floatx4 oacc[4];
#pragma unroll
        for (int f = 0; f < 4; ++f) oacc[f] = (floatx4){0.f, 0.f, 0.f, 0.f};
        float m_run = -1e30f, l_run = 0.f;
        const int qwave_min = qbase + wid * 16;
        const int qg = qwave_min + lq;

        for (int kt = 0; kt < nkv; ++kt) {
            const int cur = kt & 1;
            const int kvb = kt * 64;
            const bool pf = (kt + 1 < nkv);
            float4 kreg, vreg;
            if (pf) {   // issue next-tile loads early (latency hides under compute)
                const int kvn = kvb + 64;
                kreg = *reinterpret_cast<const float4*>(&Km[(size_t)(b * TT + kvn + srow) * DIMM + h * DHH + sdc * 8]);
                vreg = *reinterpret_cast<const float4*>(&Vbase[(size_t)srow * TT + kvn + sdc * 8]);
            }
            if (kvb <= qwave_min + 15) {   // wave-uniform causal skip
                const bool needC = (kvb + 63 > qwave_min);
                float p[4][4];
                float mt = -3.0e38f;
#pragma unroll
                for (int f = 0; f < 4; ++f) {
                    const int r = f * 16 + lq;
                    const int sw = (r & 7) << 4;
                    short8 kf0 = *reinterpret_cast<const short8*>((char*)Ks[cur] + ((r * 128 + g * 16) ^ sw));
                    short8 kf1 = *reinterpret_cast<const short8*>((char*)Ks[cur] + ((r * 128 + 64 + g * 16) ^ sw));
                    floatx4 t = (floatx4){0.f, 0.f, 0.f, 0.f};
                    t = MFMA16(kf0, qf0, t);
                    t = MFMA16(kf1, qf1, t);
                    const float4 bias = *reinterpret_cast<const float4*>(&maskF[kvb + f * 16 + g * 4]);
                    float bb[4] = {bias.x, bias.y, bias.z, bias.w};
#pragma unroll
                    for (int r2 = 0; r2 < 4; ++r2) {
                        float sv = t[r2] + bb[r2];
                        if (needC) {
                            const int kv = kvb + f * 16 + g * 4 + r2;
                            if (kv > qg) sv = -3.0e38f;
                        }
                        p[f][r2] = sv;
                        mt = fmaxf(mt, sv);
                    }
                }
                mt = fmaxf(mt, __shfl_xor(mt, 16, 64));
                mt = fmaxf(mt, __shfl_xor(mt, 32, 64));
                const float m_new = fmaxf(m_run, mt);
                const float alpha = exp2f(m_run - m_new);
                float rs = 0.f;
#pragma unroll
                for (int f = 0; f < 4; ++f)
#pragma unroll
                    for (int r2 = 0; r2 < 4; ++r2) {
                        float pe = exp2f(p[f][r2] - m_new);
                        p[f][r2] = pe;
                        rs += pe;
                    }
                rs += __shfl_xor(rs, 16, 64);
                rs += __shfl_xor(rs, 32, 64);
                l_run = l_run * alpha + rs;
                m_run = m_new;
#pragma unroll
                for (int f = 0; f < 4; ++f) oacc[f] *= alpha;
#pragma unroll
                for (int f = 0; f < 4; ++f) {
                    unsigned long long pk = (unsigned long long)pk2(p[f][0], p[f][1]) |
                                            ((unsigned long long)pk2(p[f][2], p[f][3]) << 32);
                    *reinterpret_cast<unsigned long long*>(&Ps[wid][lq * 72 + f * 16 + g * 4]) = pk;
                }
#pragma unroll
                for (int f = 0; f < 4; ++f) {
                    const int r = f * 16 + lq;
                    const int sw = (r & 7) << 4;
#pragma unroll
                    for (int kk = 0; kk < 2; ++kk) {
                        short8 av = *reinterpret_cast<const short8*>((char*)Vs[cur] + ((r * 128 + kk * 64 + g * 16) ^ sw));
                        short8 bv = *reinterpret_cast<const short8*>(&Ps[wid][lq * 72 + kk * 32 + g * 8]);
                        oacc[f] = MFMA16(av, bv, oacc[f]);
                    }
                }
            }
            if (pf) {   // write-late: vmcnt wait lands here, after compute
                *reinterpret_cast<float4*>((char*)Ks[cur ^ 1] + soff) = kreg;
                *reinterpret_cast<float4*>((char*)Vs[cur ^ 1] + soff) = vreg;
            }
            __syncthreads();
        }

        const float inv = 1.f / l_run;
#pragma unroll
        for (int f = 0; f < 4; ++f) {
            unsigned long long pk = (unsigned long long)pk2(oacc[f][0] * inv, oacc[f][1] * inv) |
                                    ((unsigned long long)pk2(oacc[f][2] * inv, oacc[f][3] * inv) << 32);
            *reinterpret_cast<unsigned long long*>(
                &O[(rowQ + wid * 16 + lq) * DIMM + h * DHH + f * 16 + g * 4]) = pk;
        }
    }
}

// ---------------------------------------------------------------------------
extern "C" void kernel_launch(void* const* d_in, const int* in_sizes, int n_in,
                              void* d_out, int out_size, void* d_ws, size_t ws_size,
                              hipStream_t stream) {
    const float* q  = (const float*)d_in[0];
    const float* k  = (const float*)d_in[1];
    const float* v  = (const float*)d_in[2];
    const float* Wq = (const float*)d_in[3];
    const float* bq = (const float*)d_in[4];
    const float* Wk = (const float*)d_in[5];
    const float* bk = (const float*)d_in[6];
    const float* Wv = (const float*)d_in[7];
    const float* bv = (const float*)d_in[8];
    const float* Wo = (const float*)d_in[9];
    const float* bo = (const float*)d_in[10];
    const unsigned char* cmask = (const unsigned char*)d_in[12];

    unsigned short* Qp  = (unsigned short*)d_ws;                   // [8192][1024]
    unsigned short* Kp  = Qp + (size_t)MM * DIMM;
    unsigned short* Vtp = Kp + (size_t)MM * DIMM;                  // [b,h,d,t]
    unsigned short* AO  = Vtp + (size_t)MM * DIMM;
    unsigned short* Wt  = AO + (size_t)MM * DIMM;                  // 4x [n][k]
    unsigned char* ctxn = (unsigned char*)(Wt + (size_t)4 * DIMM * DIMM);

    normalize_ctx<<<dim3(1), dim3(256), 0, stream>>>(cmask, ctxn);
    wtrans<<<dim3(256, 4), dim3(256), 0, stream>>>(Wq, Wk, Wv, Wo, Wt);

    // log2(e) folded into the Q scale: softmax runs in exp2 domain.
    const float scale_q = 0.125f * 1.4426950408889634f;
    gemm128<0, 0><<<dim3(64, 8), dim3(256), 0, stream>>>(q, Wt,                           bq, Qp,  MM, DIMM, DIMM, scale_q);
    gemm128<0, 0><<<dim3(64, 8), dim3(256), 0, stream>>>(k, Wt + (size_t)DIMM * DIMM,     bk, Kp,  MM, DIMM, DIMM, 1.f);
    gemm128<0, 1><<<dim3(64, 8), dim3(256), 0, stream>>>(v, Wt + (size_t)2 * DIMM * DIMM, bv, Vtp, MM, DIMM, DIMM, 1.f);

    attn128<<<dim3(BB * HH * 8), dim3(512), 0, stream>>>(Qp, Kp, Vtp, ctxn, AO);

    gemm128<1, 2><<<dim3(64, 8), dim3(256), 0, stream>>>(AO, Wt + (size_t)3 * DIMM * DIMM, bo, d_out, MM, DIMM, DIMM, 1.f);
}